// Round 4
// baseline (306.302 us; speedup 1.0000x reference)
//
#include <hip/hip_runtime.h>
#include <hip/hip_bf16.h>
#include <math.h>

// Problem constants (fixed by setup_inputs)
constexpr int B_ = 32;
constexpr int C_ = 256;
constexpr int N_ = 64;
constexpr int S_ = 64;
constexpr int NPIX = N_ * N_;        // 4096
constexpr int QB = B_ * N_;          // 2048 query blocks: (video, row)
constexpr int TOTAL_BLOCKS = S_ + QB; // video blocks first, then query
constexpr int NACC = 8;              // contention-spread copies of neg accum

#define T_V_INV 10.0f
#define T_Q_INV 10.0f
#define NEG_IOU 0.5f

typedef __attribute__((ext_vector_type(8))) short short8;
typedef __attribute__((ext_vector_type(4))) float f32x4;

static __device__ __forceinline__ unsigned short f2bf(float x) {
  __hip_bfloat16 h = __float2bfloat16(x);
  unsigned short u;
  __builtin_memcpy(&u, &h, sizeof(u));
  return u;
}

// ---------------------------------------------------------------------------
// K1 setup: blocks 0..63 = per-sentence (normalize feats -> sf_t fp32 + bf16
// MFMA A-fragments; top-1 valid pixel from iou). Block 64 = scatter_idx +
// zero-init of all cross-block accumulators (ws is poisoned every call).
// ---------------------------------------------------------------------------
__global__ __launch_bounds__(256) void k_setup(
    const float* __restrict__ sents, const float* __restrict__ iou,
    const int* __restrict__ nt,
    float* __restrict__ sf_t, unsigned short* __restrict__ sf_frag,
    int* __restrict__ scatter, int* __restrict__ top_pix,
    float* __restrict__ neg_acc, float* __restrict__ pos_score,
    float* __restrict__ loss_vid, unsigned int* __restrict__ counter) {
  int bid = blockIdx.x, tid = threadIdx.x;
  __shared__ float wsum[4];
  __shared__ float bval[256];
  __shared__ int bidx[256];

  if (bid < S_) {
    int s = bid, c = tid;
    // --- normalize sentence features ---
    float v = sents[s * C_ + c];
    float ss = v * v;
    #pragma unroll
    for (int o = 32; o; o >>= 1) ss += __shfl_xor(ss, o);
    if ((c & 63) == 0) wsum[c >> 6] = ss;
    __syncthreads();
    float tot = wsum[0] + wsum[1] + wsum[2] + wsum[3];
    float rn = 1.0f / fmaxf(sqrtf(tot), 1e-12f);
    float o = v * rn;
    sf_t[c * S_ + s] = o;
    // A-fragment layout: A[m=s][k=c], lane = quad*16 + (s&15), elem j = c&7
    int ks = c >> 5, q = (c >> 3) & 3, j = c & 7;
    int mt = s >> 4, m = s & 15;
    sf_frag[((ks * 4 + mt) * 64 + (q * 16 + m)) * 8 + j] = f2bf(o);

    // --- top-1 valid pixel (ties -> lowest flat index) ---
    float bv = -1.0f;
    int bi = 0x7fffffff;
    for (int pix = tid; pix < NPIX; pix += 256) {
      int r = pix >> 6, c0 = pix & 63;
      if (c0 >= r) {
        float x = iou[s * NPIX + pix];
        if (x > bv) { bv = x; bi = pix; }
      }
    }
    bval[tid] = bv; bidx[tid] = bi;
    __syncthreads();
    for (int st = 128; st; st >>= 1) {
      if (tid < st) {
        float ov = bval[tid + st]; int oi = bidx[tid + st];
        if (ov > bval[tid] || (ov == bval[tid] && oi < bidx[tid])) {
          bval[tid] = ov; bidx[tid] = oi;
        }
      }
      __syncthreads();
    }
    if (tid == 0) top_pix[s] = bidx[0];
  } else {
    // --- scatter_idx + accumulator zero-init ---
    if (tid < S_) {
      int cum = 0, res = 0;
      for (int b = 0; b < B_; b++) {
        int nb = nt[b];
        if (tid >= cum && tid < cum + nb) res = b;
        cum += nb;
      }
      scatter[tid] = res;
    }
    for (int i = tid; i < NACC * S_; i += 256) neg_acc[i] = 0.0f;
    if (tid >= 64 && tid < 128) pos_score[tid - 64] = 0.0f;
    if (tid >= 128 && tid < 192) loss_vid[tid - 128] = 0.0f;
    if (tid == 0) *counter = 0u;
  }
}

// ---------------------------------------------------------------------------
// K2 main: blocks [0,64) = per-sentence inter-video loss (dispatched first,
// hidden under the query blocks). Blocks [64, 64+QB) = inter-query MFMA score
// GEMM + fused normalize/exp/mask, block-reduced then atomicAdd'ed into
// contention-spread global accumulators. Last-arriving block computes both
// losses and writes d_out (device-scope atomic counter + threadfence).
// ---------------------------------------------------------------------------
__global__ __launch_bounds__(256) void k_main(
    const float* __restrict__ V, const float* __restrict__ iou,
    const short8* __restrict__ Afrag, const float* __restrict__ sf_t,
    const int* __restrict__ scatter, const int* __restrict__ top_pix,
    float* __restrict__ neg_acc, float* __restrict__ pos_score,
    float* __restrict__ loss_vid, unsigned int* __restrict__ counter,
    float* __restrict__ out) {
  __shared__ int ssc[S_];
  __shared__ float part[4][S_];
  __shared__ float vh[C_];
  __shared__ float red[4];
  __shared__ float pdm[4][S_];
  __shared__ int sIsLast;

  int tid = threadIdx.x;

  if (blockIdx.x >= S_) {
    // ============ inter-query path ============
    if (tid < S_) ssc[tid] = scatter[tid];
    __syncthreads();

    int qb = blockIdx.x - S_;
    int b = qb >> 6, r = qb & 63;
    int w = tid >> 6, lane = tid & 63;
    int n = lane & 15, q = lane >> 4;
    int col = w * 16 + n;
    int pix = r * 64 + col;
    bool active = (col >= r); // triangle mask

    const float* vb = V + (size_t)b * C_ * NPIX + pix;
    f32x4 acc[4] = {f32x4{0,0,0,0}, f32x4{0,0,0,0}, f32x4{0,0,0,0}, f32x4{0,0,0,0}};
    float ssq = 0.0f;

    for (int ks = 0; ks < 8; ks++) {
      short8 bfrag;
      #pragma unroll
      for (int j = 0; j < 8; j++) {
        int c = ks * 32 + q * 8 + j; // B[k][n]: k=quad*8+j, n=lane&15
        float v = active ? vb[(size_t)c * NPIX] : 0.0f;
        ssq = fmaf(v, v, ssq);
        bfrag[j] = (short)f2bf(v);
      }
      #pragma unroll
      for (int mt = 0; mt < 4; mt++) {
        short8 a = Afrag[(ks * 4 + mt) * 64 + lane];
        acc[mt] = __builtin_amdgcn_mfma_f32_16x16x32_bf16(a, bfrag, acc[mt], 0, 0, 0);
      }
    }

    ssq += __shfl_xor(ssq, 16);
    ssq += __shfl_xor(ssq, 32);
    float rs = T_Q_INV / fmaxf(sqrtf(ssq), 1e-12f);

    // Epilogue: D layout col(pix)=lane&15, row(sent)=quad*4+rr
    #pragma unroll
    for (int mt = 0; mt < 4; mt++) {
      #pragma unroll
      for (int rr = 0; rr < 4; rr++) {
        int s = mt * 16 + q * 4 + rr;
        float e = active ? __expf(acc[mt][rr] * rs) : 0.0f;
        if (active && ssc[s] == b) {
          if (iou[s * NPIX + pix] > NEG_IOU) e = 0.0f; // positive -> not a negative
        }
        e += __shfl_xor(e, 1);
        e += __shfl_xor(e, 2);
        e += __shfl_xor(e, 4);
        e += __shfl_xor(e, 8); // summed over this wave's 16 pixels
        if (n == 0) part[w][s] = e;
      }
    }
    __syncthreads();
    if (tid < S_) {
      float v = part[0][tid] + part[1][tid] + part[2][tid] + part[3][tid];
      atomicAdd(&neg_acc[(qb & (NACC - 1)) * S_ + tid], v);
    }
  } else {
    // ============ inter-video path (one block per sentence) ============
    int s = blockIdx.x;
    int b = scatter[s];
    int pix = top_pix[s];
    float v = V[((size_t)b * C_ + tid) * NPIX + pix];
    float ss = v * v;
    #pragma unroll
    for (int o = 32; o; o >>= 1) ss += __shfl_xor(ss, o);
    if ((tid & 63) == 0) red[tid >> 6] = ss;
    __syncthreads();
    float tot = red[0] + red[1] + red[2] + red[3];
    float rn = 1.0f / fmaxf(sqrtf(tot), 1e-12f);
    vh[tid] = v * rn;
    __syncthreads();
    int so = tid & 63, chunk = tid >> 6;
    float pd = 0.0f;
    #pragma unroll 8
    for (int c = chunk * 64; c < chunk * 64 + 64; c++)
      pd = fmaf(vh[c], sf_t[c * S_ + so], pd);
    pdm[chunk][so] = pd;
    __syncthreads();
    if (tid < S_) {
      float dot = pdm[0][tid] + pdm[1][tid] + pdm[2][tid] + pdm[3][tid];
      if (tid == s) atomicAdd(&pos_score[s], dot);
      float pos = __shfl(dot, s);
      float e = (tid == s) ? 0.0f : __expf(dot * T_V_INV);
      #pragma unroll
      for (int o = 32; o; o >>= 1) e += __shfl_xor(e, o);
      if (tid == 0) {
        float pp = pos * T_V_INV;
        atomicAdd(&loss_vid[s], -(pp - logf(__expf(pp) + e)));
      }
    }
  }

  // ============ last-block tail ============
  __syncthreads();
  if (tid == 0) {
    __threadfence(); // release: prior atomics/stores visible device-wide
    unsigned int old = atomicAdd(counter, 1u);
    sIsLast = (old == (unsigned int)(TOTAL_BLOCKS - 1));
  }
  __syncthreads();
  if (sIsLast) {
    __threadfence(); // acquire
    if (tid < S_) {
      float neg = 0.0f;
      #pragma unroll
      for (int k = 0; k < NACC; k++)
        neg += atomicAdd(&neg_acc[k * S_ + tid], 0.0f); // coherent read
      float ps = atomicAdd(&pos_score[tid], 0.0f);
      float lv = atomicAdd(&loss_vid[tid], 0.0f);
      float p = ps * T_Q_INV;
      float lq = -(p - logf(__expf(p) + neg));
      #pragma unroll
      for (int o = 32; o; o >>= 1) {
        lq += __shfl_xor(lq, o);
        lv += __shfl_xor(lv, o);
      }
      if (tid == 0) {
        out[0] = lv / (float)S_;
        out[1] = lq / (float)S_;
      }
    }
  }
}

// ---------------------------------------------------------------------------
extern "C" void kernel_launch(void* const* d_in, const int* in_sizes, int n_in,
                              void* d_out, int out_size, void* d_ws, size_t ws_size,
                              hipStream_t stream) {
  const float* V     = (const float*)d_in[0]; // [B,C,N,N]
  const float* sents = (const float*)d_in[1]; // [S,C]
  const int*   nt    = (const int*)d_in[2];   // [B]
  const float* iou   = (const float*)d_in[3]; // [S,N,N]
  // d_in[4] = mask2d: structural triu — resolved statically (as in reference)

  float* ws = (float*)d_ws;
  float*          sf_t    = ws;                            // 16384 floats
  unsigned short* sf_frag = (unsigned short*)(ws + 16384); // 16384 bf16
  int*   scatter   = (int*)(ws + 16384 + 8192);
  int*   top_pix   = scatter + S_;
  float* pos_score = (float*)(top_pix + S_);
  float* loss_vid  = pos_score + S_;
  float* neg_acc   = loss_vid + S_;                        // NACC*S_ floats
  unsigned int* counter = (unsigned int*)(neg_acc + NACC * S_);

  k_setup<<<S_ + 1, 256, 0, stream>>>(sents, iou, nt, sf_t, sf_frag, scatter,
                                      top_pix, neg_acc, pos_score, loss_vid,
                                      counter);
  k_main <<<TOTAL_BLOCKS, 256, 0, stream>>>(V, iou, (const short8*)sf_frag,
                                            sf_t, scatter, top_pix, neg_acc,
                                            pos_score, loss_vid, counter,
                                            (float*)d_out);
}

// Round 5
// 248.618 us; speedup vs baseline: 1.2320x; 1.2320x over previous
//
#include <hip/hip_runtime.h>
#include <hip/hip_bf16.h>
#include <math.h>

// Problem constants (fixed by setup_inputs)
constexpr int B_ = 32;
constexpr int C_ = 256;
constexpr int N_ = 64;
constexpr int S_ = 64;
constexpr int NPIX = N_ * N_;   // 4096
constexpr int QB = B_ * N_;     // 2048 query blocks: (video, row)

#define T_V_INV 10.0f
#define T_Q_INV 10.0f
#define NEG_IOU 0.5f

typedef __attribute__((ext_vector_type(8))) short short8;
typedef __attribute__((ext_vector_type(4))) float f32x4;
typedef __attribute__((ext_vector_type(4))) unsigned short ushort4_;

static __device__ __forceinline__ unsigned short f2bf(float x) {
  __hip_bfloat16 h = __float2bfloat16(x);
  unsigned short u;
  __builtin_memcpy(&u, &h, sizeof(u));
  return u;
}
static __device__ __forceinline__ float bf2f(unsigned short u) {
  unsigned int ui = ((unsigned int)u) << 16;
  float f;
  __builtin_memcpy(&f, &ui, 4);
  return f;
}

// ---------------------------------------------------------------------------
// K1 setup: blocks 0..63 = per-sentence (normalize feats -> sf_t fp32 + bf16
// MFMA A-fragments; top-1 valid pixel from iou). Block 64 = scatter_idx.
// ---------------------------------------------------------------------------
__global__ __launch_bounds__(256) void k_setup(
    const float* __restrict__ sents, const float* __restrict__ iou,
    const int* __restrict__ nt,
    float* __restrict__ sf_t, unsigned short* __restrict__ sf_frag,
    int* __restrict__ scatter, int* __restrict__ top_pix) {
  int bid = blockIdx.x, tid = threadIdx.x;
  __shared__ float wsum[4];
  __shared__ float bval[256];
  __shared__ int bidx[256];

  if (bid < S_) {
    int s = bid, c = tid;
    float v = sents[s * C_ + c];
    float ss = v * v;
    #pragma unroll
    for (int o = 32; o; o >>= 1) ss += __shfl_xor(ss, o);
    if ((c & 63) == 0) wsum[c >> 6] = ss;
    __syncthreads();
    float tot = wsum[0] + wsum[1] + wsum[2] + wsum[3];
    float rn = 1.0f / fmaxf(sqrtf(tot), 1e-12f);
    float o = v * rn;
    sf_t[c * S_ + s] = o;
    // A-fragment layout: A[m=s][k=c], lane = quad*16 + (s&15), elem j = c&7
    int ks = c >> 5, q = (c >> 3) & 3, j = c & 7;
    int mt = s >> 4, m = s & 15;
    sf_frag[((ks * 4 + mt) * 64 + (q * 16 + m)) * 8 + j] = f2bf(o);

    // top-1 valid pixel (ties -> lowest flat index)
    float bv = -1.0f;
    int bi = 0x7fffffff;
    for (int pix = tid; pix < NPIX; pix += 256) {
      int r = pix >> 6, c0 = pix & 63;
      if (c0 >= r) {
        float x = iou[s * NPIX + pix];
        if (x > bv) { bv = x; bi = pix; }
      }
    }
    bval[tid] = bv; bidx[tid] = bi;
    __syncthreads();
    for (int st = 128; st; st >>= 1) {
      if (tid < st) {
        float ov = bval[tid + st]; int oi = bidx[tid + st];
        if (ov > bval[tid] || (ov == bval[tid] && oi < bidx[tid])) {
          bval[tid] = ov; bidx[tid] = oi;
        }
      }
      __syncthreads();
    }
    if (tid == 0) top_pix[s] = bidx[0];
  } else {
    if (tid < S_) {
      int cum = 0, res = 0;
      for (int b = 0; b < B_; b++) {
        int nb = nt[b];
        if (tid >= cum && tid < cum + nb) res = b;
        cum += nb;
      }
      scatter[tid] = res;
    }
  }
}

// ---------------------------------------------------------------------------
// K2 main: blocks [0,QB) = inter-query MFMA score GEMM.
//   Per block (b, r): loop over 8 ks-tiles of 32 c. Load phase: 256 threads
//   read float4 (4 consecutive pixels of one c) — 1 KB contiguous per
//   wave-instruction, triangle-masked — convert to bf16, stage in LDS tile
//   [32 c][64+pad pix]. MFMA phase: lane(n,q) gathers its 8-c B-fragment
//   from LDS; 4 M-tiles of 16x16x32 accumulate all 64 sentences.
// Blocks [QB, QB+64) = per-sentence inter-video loss.
// NO device atomics / fences (round-4 post-mortem: they cost ~2x on k_main).
// ---------------------------------------------------------------------------
__global__ __launch_bounds__(256) void k_main(
    const float* __restrict__ V, const float* __restrict__ iou,
    const short8* __restrict__ Afrag, const float* __restrict__ sf_t,
    const int* __restrict__ scatter, const int* __restrict__ top_pix,
    float* __restrict__ partials, float* __restrict__ pos_score,
    float* __restrict__ loss_vid) {
  __shared__ int ssc[S_];
  __shared__ float part[4][S_];
  __shared__ unsigned short tile[32][68]; // row stride 136B (8-aligned, padded)
  __shared__ float vh[C_];
  __shared__ float red[4];
  __shared__ float pdm[4][S_];

  int tid = threadIdx.x;

  if (blockIdx.x < QB) {
    // ============ inter-query path ============
    if (tid < S_) ssc[tid] = scatter[tid];

    int b = blockIdx.x >> 6, r = blockIdx.x & 63;
    int w = tid >> 6, lane = tid & 63;
    int n = lane & 15, q = lane >> 4;
    int col = w * 16 + n;
    int pix = r * 64 + col;
    bool active = (col >= r); // triangle mask

    const float* vbase = V + (size_t)b * C_ * NPIX + r * 64;
    f32x4 acc[4] = {f32x4{0,0,0,0}, f32x4{0,0,0,0}, f32x4{0,0,0,0}, f32x4{0,0,0,0}};
    float ssq = 0.0f;
    __syncthreads(); // ssc visible

    for (int ks = 0; ks < 8; ks++) {
      // ---- load phase: 2 wide loads/thread, 1KB contiguous per wave-instr
      #pragma unroll
      for (int i = 0; i < 2; i++) {
        int flat = i * 1024 + tid * 4;     // [0,2048) floats of this ks-tile
        int cc = flat >> 6, pp = flat & 63; // c-within-tile, pixel col
        if (pp + 3 >= r) {                  // skip fully-invalid float4s
          f32x4 v4 = *(const f32x4*)(vbase + (size_t)(ks * 32 + cc) * NPIX + pp);
          ushort4_ u;
          u.x = f2bf(v4.x); u.y = f2bf(v4.y);
          u.z = f2bf(v4.z); u.w = f2bf(v4.w);
          *(ushort4_*)&tile[cc][pp] = u;    // ds_write_b64
        }
      }
      __syncthreads();
      // ---- MFMA phase: gather B-fragment (8 c for this lane's pixel)
      short8 bfrag;
      #pragma unroll
      for (int j = 0; j < 8; j++) {
        int cc = q * 8 + j; // c = ks*32 + quad*8 + j  (B[k][n] layout)
        unsigned short u = active ? tile[cc][col] : (unsigned short)0;
        bfrag[j] = (short)u;
        float f = bf2f(u);
        ssq = fmaf(f, f, ssq);
      }
      #pragma unroll
      for (int mt = 0; mt < 4; mt++) {
        short8 a = Afrag[(ks * 4 + mt) * 64 + lane];
        acc[mt] = __builtin_amdgcn_mfma_f32_16x16x32_bf16(a, bfrag, acc[mt], 0, 0, 0);
      }
      __syncthreads(); // tile reuse
    }

    // fold quads -> full per-pixel sum of squares
    ssq += __shfl_xor(ssq, 16);
    ssq += __shfl_xor(ssq, 32);
    float rs = T_Q_INV / fmaxf(sqrtf(ssq), 1e-12f);

    // Epilogue: D layout col(pix)=lane&15, row(sent)=quad*4+rr
    #pragma unroll
    for (int mt = 0; mt < 4; mt++) {
      #pragma unroll
      for (int rr = 0; rr < 4; rr++) {
        int s = mt * 16 + q * 4 + rr;
        float e = active ? __expf(acc[mt][rr] * rs) : 0.0f;
        if (active && ssc[s] == b) {
          if (iou[s * NPIX + pix] > NEG_IOU) e = 0.0f; // positive -> excluded
        }
        e += __shfl_xor(e, 1);
        e += __shfl_xor(e, 2);
        e += __shfl_xor(e, 4);
        e += __shfl_xor(e, 8); // summed over this wave's 16 pixels
        if (n == 0) part[w][s] = e;
      }
    }
    __syncthreads();
    if (tid < S_) {
      partials[(size_t)blockIdx.x * S_ + tid] =
          part[0][tid] + part[1][tid] + part[2][tid] + part[3][tid];
    }
  } else {
    // ============ inter-video path (one block per sentence) ============
    int s = blockIdx.x - QB;
    int b = scatter[s];
    int pix = top_pix[s];
    float v = V[((size_t)b * C_ + tid) * NPIX + pix];
    float ss = v * v;
    #pragma unroll
    for (int o = 32; o; o >>= 1) ss += __shfl_xor(ss, o);
    if ((tid & 63) == 0) red[tid >> 6] = ss;
    __syncthreads();
    float tot = red[0] + red[1] + red[2] + red[3];
    float rn = 1.0f / fmaxf(sqrtf(tot), 1e-12f);
    vh[tid] = v * rn;
    __syncthreads();
    int so = tid & 63, chunk = tid >> 6;
    float pd = 0.0f;
    #pragma unroll 8
    for (int c = chunk * 64; c < chunk * 64 + 64; c++)
      pd = fmaf(vh[c], sf_t[c * S_ + so], pd);
    pdm[chunk][so] = pd;
    __syncthreads();
    if (tid < S_) {
      float dot = pdm[0][tid] + pdm[1][tid] + pdm[2][tid] + pdm[3][tid];
      if (tid == s) pos_score[s] = dot;
      float pos = __shfl(dot, s);
      float e = (tid == s) ? 0.0f : __expf(dot * T_V_INV);
      #pragma unroll
      for (int o = 32; o; o >>= 1) e += __shfl_xor(e, o);
      if (tid == 0) {
        float pp = pos * T_V_INV;
        loss_vid[s] = -(pp - logf(__expf(pp) + e));
      }
    }
  }
}

// ---------------------------------------------------------------------------
// K3 tail: single 1024-thread block. Reduce partials -> per-sentence negative
// sums, compute both losses, write the two means.
// ---------------------------------------------------------------------------
__global__ __launch_bounds__(1024) void k_tail(
    const float* __restrict__ partials, const float* __restrict__ pos_score,
    const float* __restrict__ loss_vid, float* __restrict__ out) {
  int tid = threadIdx.x;            // 1024
  int s = tid & 63, g = tid >> 6;   // 16 groups x 64 sentences
  __shared__ float m[16][S_];
  float acc = 0.0f;
  for (int blk = g; blk < QB; blk += 16) acc += partials[(size_t)blk * S_ + s];
  m[g][s] = acc;
  __syncthreads();
  if (tid < S_) {
    float neg = 0.0f;
    #pragma unroll
    for (int gg = 0; gg < 16; gg++) neg += m[gg][tid];
    float p = pos_score[tid] * T_Q_INV;
    float lq = -(p - logf(__expf(p) + neg));
    float lv = loss_vid[tid];
    #pragma unroll
    for (int o = 32; o; o >>= 1) {
      lq += __shfl_xor(lq, o);
      lv += __shfl_xor(lv, o);
    }
    if (tid == 0) {
      out[0] = lv / (float)S_;
      out[1] = lq / (float)S_;
    }
  }
}

// ---------------------------------------------------------------------------
extern "C" void kernel_launch(void* const* d_in, const int* in_sizes, int n_in,
                              void* d_out, int out_size, void* d_ws, size_t ws_size,
                              hipStream_t stream) {
  const float* V     = (const float*)d_in[0]; // [B,C,N,N]
  const float* sents = (const float*)d_in[1]; // [S,C]
  const int*   nt    = (const int*)d_in[2];   // [B]
  const float* iou   = (const float*)d_in[3]; // [S,N,N]
  // d_in[4] = mask2d: structural triu — resolved statically (as in reference)

  float* ws = (float*)d_ws;
  float*          sf_t    = ws;                            // 16384 floats
  unsigned short* sf_frag = (unsigned short*)(ws + 16384); // 16384 bf16
  int*   scatter   = (int*)(ws + 16384 + 8192);
  int*   top_pix   = scatter + S_;
  float* pos_score = (float*)(top_pix + S_);
  float* loss_vid  = pos_score + S_;
  float* partials  = loss_vid + S_;                        // QB*S_ floats

  k_setup<<<S_ + 1, 256, 0, stream>>>(sents, iou, nt, sf_t, sf_frag, scatter, top_pix);
  k_main <<<QB + S_, 256, 0, stream>>>(V, iou, (const short8*)sf_frag, sf_t,
                                       scatter, top_pix, partials, pos_score, loss_vid);
  k_tail <<<1, 1024, 0, stream>>>(partials, pos_score, loss_vid, (float*)d_out);
}

// Round 6
// 219.348 us; speedup vs baseline: 1.3964x; 1.1334x over previous
//
#include <hip/hip_runtime.h>
#include <hip/hip_bf16.h>
#include <math.h>

// Problem constants (fixed by setup_inputs)
constexpr int B_ = 32;
constexpr int C_ = 256;
constexpr int N_ = 64;
constexpr int S_ = 64;
constexpr int NPIX = N_ * N_;   // 4096
constexpr int QB = B_ * N_;     // 2048 query blocks: (video, row)
constexpr int RG = 32;          // stage-1 reduction blocks

#define T_V_INV 10.0f
#define T_Q_INV 10.0f
#define NEG_IOU 0.5f

typedef __attribute__((ext_vector_type(8))) short short8;
typedef __attribute__((ext_vector_type(4))) float f32x4;

static __device__ __forceinline__ unsigned short f2bf(float x) {
  __hip_bfloat16 h = __float2bfloat16(x);
  unsigned short u;
  __builtin_memcpy(&u, &h, sizeof(u));
  return u;
}

// ---------------------------------------------------------------------------
// K1 setup: blocks 0..63 = per-sentence (normalize feats -> sf_t fp32 + bf16
// MFMA A-fragments; top-1 valid pixel from iou). Block 64 = scatter_idx.
// ---------------------------------------------------------------------------
__global__ __launch_bounds__(256) void k_setup(
    const float* __restrict__ sents, const float* __restrict__ iou,
    const int* __restrict__ nt,
    float* __restrict__ sf_t, unsigned short* __restrict__ sf_frag,
    int* __restrict__ scatter, int* __restrict__ top_pix) {
  int bid = blockIdx.x, tid = threadIdx.x;
  __shared__ float wsum[4];
  __shared__ float bval[256];
  __shared__ int bidx[256];

  if (bid < S_) {
    int s = bid, c = tid;
    float v = sents[s * C_ + c];
    float ss = v * v;
    #pragma unroll
    for (int o = 32; o; o >>= 1) ss += __shfl_xor(ss, o);
    if ((c & 63) == 0) wsum[c >> 6] = ss;
    __syncthreads();
    float tot = wsum[0] + wsum[1] + wsum[2] + wsum[3];
    float rn = 1.0f / fmaxf(sqrtf(tot), 1e-12f);
    float o = v * rn;
    sf_t[c * S_ + s] = o;
    // A-fragment layout: A[m=s][k=c], lane = quad*16 + (s&15), elem j = c&7
    int ks = c >> 5, q = (c >> 3) & 3, j = c & 7;
    int mt = s >> 4, m = s & 15;
    sf_frag[((ks * 4 + mt) * 64 + (q * 16 + m)) * 8 + j] = f2bf(o);

    // top-1 valid pixel (ties -> lowest flat index)
    float bv = -1.0f;
    int bi = 0x7fffffff;
    for (int pix = tid; pix < NPIX; pix += 256) {
      int r = pix >> 6, c0 = pix & 63;
      if (c0 >= r) {
        float x = iou[s * NPIX + pix];
        if (x > bv) { bv = x; bi = pix; }
      }
    }
    bval[tid] = bv; bidx[tid] = bi;
    __syncthreads();
    for (int st = 128; st; st >>= 1) {
      if (tid < st) {
        float ov = bval[tid + st]; int oi = bidx[tid + st];
        if (ov > bval[tid] || (ov == bval[tid] && oi < bidx[tid])) {
          bval[tid] = ov; bidx[tid] = oi;
        }
      }
      __syncthreads();
    }
    if (tid == 0) top_pix[s] = bidx[0];
  } else {
    if (tid < S_) {
      int cum = 0, res = 0;
      for (int b = 0; b < B_; b++) {
        int nb = nt[b];
        if (tid >= cum && tid < cum + nb) res = b;
        cum += nb;
      }
      scatter[tid] = res;
    }
  }
}

// ---------------------------------------------------------------------------
// K2 main: blocks [0,QB) = inter-query MFMA score GEMM + fused normalize/
// exp/mask/partial-reduce (r3-proven inner loop: direct global B-fragment
// loads, 4x64B per wave-instr). Blocks [QB, QB+64) = inter-video loss.
// ---------------------------------------------------------------------------
__global__ __launch_bounds__(256) void k_main(
    const float* __restrict__ V, const float* __restrict__ iou,
    const short8* __restrict__ Afrag, const float* __restrict__ sf_t,
    const int* __restrict__ scatter, const int* __restrict__ top_pix,
    float* __restrict__ partials, float* __restrict__ pos_score,
    float* __restrict__ loss_vid) {
  __shared__ int ssc[S_];
  __shared__ float part[4][S_];
  __shared__ float vh[C_];
  __shared__ float red[4];
  __shared__ float pdm[4][S_];

  int tid = threadIdx.x;

  if (blockIdx.x < QB) {
    // ============ inter-query path ============
    if (tid < S_) ssc[tid] = scatter[tid];
    __syncthreads();

    int b = blockIdx.x >> 6, r = blockIdx.x & 63;
    int w = tid >> 6, lane = tid & 63;
    int n = lane & 15, q = lane >> 4;
    int col = w * 16 + n;
    int pix = r * 64 + col;
    bool active = (col >= r); // triangle mask

    const float* vb = V + (size_t)b * C_ * NPIX + pix;
    f32x4 acc[4] = {f32x4{0,0,0,0}, f32x4{0,0,0,0}, f32x4{0,0,0,0}, f32x4{0,0,0,0}};
    float ssq = 0.0f;

    for (int ks = 0; ks < 8; ks++) {
      short8 bfrag;
      #pragma unroll
      for (int j = 0; j < 8; j++) {
        int c = ks * 32 + q * 8 + j; // B[k][n]: k=quad*8+j, n=lane&15
        float v = active ? vb[(size_t)c * NPIX] : 0.0f;
        ssq = fmaf(v, v, ssq);
        bfrag[j] = (short)f2bf(v);
      }
      #pragma unroll
      for (int mt = 0; mt < 4; mt++) {
        short8 a = Afrag[(ks * 4 + mt) * 64 + lane];
        acc[mt] = __builtin_amdgcn_mfma_f32_16x16x32_bf16(a, bfrag, acc[mt], 0, 0, 0);
      }
    }

    ssq += __shfl_xor(ssq, 16);
    ssq += __shfl_xor(ssq, 32);
    float rs = T_Q_INV / fmaxf(sqrtf(ssq), 1e-12f);

    // Epilogue: D layout col(pix)=lane&15, row(sent)=quad*4+rr
    #pragma unroll
    for (int mt = 0; mt < 4; mt++) {
      #pragma unroll
      for (int rr = 0; rr < 4; rr++) {
        int s = mt * 16 + q * 4 + rr;
        float e = active ? __expf(acc[mt][rr] * rs) : 0.0f;
        if (active && ssc[s] == b) {
          if (iou[s * NPIX + pix] > NEG_IOU) e = 0.0f; // positive -> excluded
        }
        e += __shfl_xor(e, 1);
        e += __shfl_xor(e, 2);
        e += __shfl_xor(e, 4);
        e += __shfl_xor(e, 8); // summed over this wave's 16 pixels
        if (n == 0) part[w][s] = e;
      }
    }
    __syncthreads();
    if (tid < S_) {
      partials[(size_t)blockIdx.x * S_ + tid] =
          part[0][tid] + part[1][tid] + part[2][tid] + part[3][tid];
    }
  } else {
    // ============ inter-video path (one block per sentence) ============
    int s = blockIdx.x - QB;
    int b = scatter[s];
    int pix = top_pix[s];
    float v = V[((size_t)b * C_ + tid) * NPIX + pix];
    float ss = v * v;
    #pragma unroll
    for (int o = 32; o; o >>= 1) ss += __shfl_xor(ss, o);
    if ((tid & 63) == 0) red[tid >> 6] = ss;
    __syncthreads();
    float tot = red[0] + red[1] + red[2] + red[3];
    float rn = 1.0f / fmaxf(sqrtf(tot), 1e-12f);
    vh[tid] = v * rn;
    __syncthreads();
    int so = tid & 63, chunk = tid >> 6;
    float pd = 0.0f;
    #pragma unroll 8
    for (int c = chunk * 64; c < chunk * 64 + 64; c++)
      pd = fmaf(vh[c], sf_t[c * S_ + so], pd);
    pdm[chunk][so] = pd;
    __syncthreads();
    if (tid < S_) {
      float dot = pdm[0][tid] + pdm[1][tid] + pdm[2][tid] + pdm[3][tid];
      if (tid == s) pos_score[s] = dot;
      float pos = __shfl(dot, s);
      float e = (tid == s) ? 0.0f : __expf(dot * T_V_INV);
      #pragma unroll
      for (int o = 32; o; o >>= 1) e += __shfl_xor(e, o);
      if (tid == 0) {
        float pp = pos * T_V_INV;
        loss_vid[s] = -(pp - logf(__expf(pp) + e));
      }
    }
  }
}

// ---------------------------------------------------------------------------
// K3 stage-1 reduce: 32 blocks x 256 threads. Block g reduces partial rows
// [g*64, (g+1)*64) -> neg1[g][s]. All reads coalesced 256B/wave-instr.
// ---------------------------------------------------------------------------
__global__ __launch_bounds__(256) void k_red(
    const float* __restrict__ partials, float* __restrict__ neg1) {
  int g = blockIdx.x, tid = threadIdx.x;
  int j = tid >> 6, s = tid & 63; // 4 j-groups x 64 sentences
  __shared__ float m[4][S_];
  float acc = 0.0f;
  #pragma unroll
  for (int k = 0; k < 16; k++)
    acc += partials[(size_t)((g * 64 + j * 16 + k)) * S_ + s];
  m[j][s] = acc;
  __syncthreads();
  if (tid < S_)
    neg1[g * S_ + tid] = m[0][tid] + m[1][tid] + m[2][tid] + m[3][tid];
}

// ---------------------------------------------------------------------------
// K4 final: 1 block x 256 threads. Fold neg1[32][64] -> neg[s]; compute both
// losses; write the two means.
// ---------------------------------------------------------------------------
__global__ __launch_bounds__(256) void k_fin(
    const float* __restrict__ neg1, const float* __restrict__ pos_score,
    const float* __restrict__ loss_vid, float* __restrict__ out) {
  int tid = threadIdx.x;
  int j = tid >> 6, s = tid & 63;
  __shared__ float m[4][S_];
  float acc = 0.0f;
  #pragma unroll
  for (int i = 0; i < 8; i++) acc += neg1[(j * 8 + i) * S_ + s];
  m[j][s] = acc;
  __syncthreads();
  if (tid < S_) {
    float neg = m[0][tid] + m[1][tid] + m[2][tid] + m[3][tid];
    float p = pos_score[tid] * T_Q_INV;
    float lq = -(p - logf(__expf(p) + neg));
    float lv = loss_vid[tid];
    #pragma unroll
    for (int o = 32; o; o >>= 1) {
      lq += __shfl_xor(lq, o);
      lv += __shfl_xor(lv, o);
    }
    if (tid == 0) {
      out[0] = lv / (float)S_;
      out[1] = lq / (float)S_;
    }
  }
}

// ---------------------------------------------------------------------------
extern "C" void kernel_launch(void* const* d_in, const int* in_sizes, int n_in,
                              void* d_out, int out_size, void* d_ws, size_t ws_size,
                              hipStream_t stream) {
  const float* V     = (const float*)d_in[0]; // [B,C,N,N]
  const float* sents = (const float*)d_in[1]; // [S,C]
  const int*   nt    = (const int*)d_in[2];   // [B]
  const float* iou   = (const float*)d_in[3]; // [S,N,N]
  // d_in[4] = mask2d: structural triu — resolved statically (as in reference)

  float* ws = (float*)d_ws;
  float*          sf_t    = ws;                            // 16384 floats
  unsigned short* sf_frag = (unsigned short*)(ws + 16384); // 16384 bf16
  int*   scatter   = (int*)(ws + 16384 + 8192);
  int*   top_pix   = scatter + S_;
  float* pos_score = (float*)(top_pix + S_);
  float* loss_vid  = pos_score + S_;
  float* partials  = loss_vid + S_;                        // QB*S_ floats
  float* neg1      = partials + (size_t)QB * S_;           // RG*S_ floats

  k_setup<<<S_ + 1, 256, 0, stream>>>(sents, iou, nt, sf_t, sf_frag, scatter, top_pix);
  k_main <<<QB + S_, 256, 0, stream>>>(V, iou, (const short8*)sf_frag, sf_t,
                                       scatter, top_pix, partials, pos_score, loss_vid);
  k_red  <<<RG, 256, 0, stream>>>(partials, neg1);
  k_fin  <<<1, 256, 0, stream>>>(neg1, pos_score, loss_vid, (float*)d_out);
}